// Round 9
// baseline (139.474 us; speedup 1.0000x reference)
//
#include <hip/hip_runtime.h>

// Problem dims (fixed by reference)
#define BB 4
#define LL 1024
#define DD 64
#define UU 32
#define NW 4      // waves per block = query rows per block (1 row per wave)
#define NT 256    // threads per block
#define JH 512    // j's per half (j-split: 2 halves)
#define NTILE 8   // JH / 64

// ---------------------------------------------------------------------------
// K1: Ek[b,l,u] = exp(2*(inp@Wx)), plain row-major [l][u] layout:
// one thread's 8 u-quads are CONTIGUOUS -> phase A loads 8 x b128 from a
// single base address with immediate offsets (R4 proved coalescing of these
// loads doesn't matter; address-calc count does).
// tanh(q+k+bh) = 1 - 2/(1 + Eq*Ek); Eq computed per-block inside attn.
// ---------------------------------------------------------------------------
__global__ __launch_bounds__(256) void precompute_kernel(
    const float* __restrict__ inp, const float* __restrict__ Wx,
    float* __restrict__ Ek)
{
    __shared__ float s_in[8][DD];       // 2 KB
    __shared__ float s_wx[DD][UU];      // 8 KB
    int t = threadIdx.x;
    int row0 = blockIdx.x * 8;
    if (t < 128)
        ((float4*)s_in)[t] = ((const float4*)(inp + (size_t)row0 * DD))[t];
#pragma unroll
    for (int p = 0; p < 2; ++p)
        ((float4*)s_wx)[p * 256 + t] = ((const float4*)Wx)[p * 256 + t];
    __syncthreads();
    int r = t >> 5;
    int u = t & 31;
    float k = 0.f;
#pragma unroll
    for (int d = 0; d < DD; ++d)
        k = fmaf(s_in[r][d], s_wx[d][u], k);
    Ek[(size_t)(row0 + r) * UU + u] = __expf(2.f * k);   // coalesced
}

// ---------------------------------------------------------------------------
// K2: wave-per-row j-split partial attention. block = 4 waves = 4 rows x 512
// j's; grid = 2048 (8 blocks/CU co-resident, 32 waves/CU).
// Phase A: eq in SGPRs (readlane), ek 8xb128 one-base-addr, e[8] in VGPRs —
// ZERO LDS. Softmax in-wave, in-register. ONE transposed LDS write pass
// (at[j][w], 8-way-conflict scalar writes), phase B reads 1 ds_read_b128/iter.
// ---------------------------------------------------------------------------
union ShMem {
    struct { float wt[DD][UU]; float in[NW][DD]; } pre;  // 9.25 KB staging
    float at[JH][NW];                                     // 8 KB ex^T table
};

__global__ __launch_bounds__(NT) void attn_partial_kernel(
    const float* __restrict__ Ek, const float* __restrict__ inp,
    const float* __restrict__ Wt, const float* __restrict__ Wa,
    const float* __restrict__ bh,
    float* __restrict__ po, float* __restrict__ pm, float* __restrict__ ps)
{
    __shared__ ShMem sh;
    __shared__ float  s_eq[NW][UU];     // 512 B
    __shared__ float4 s_v[NW][NW][16];  // 4 KB epilogue partials

    int t    = threadIdx.x;
    int w    = t >> 6;                  // wave 0..3 = local row
    int lane = t & 63;
    int bid  = blockIdx.x;
    int q    = bid >> 1;                // row-quad 0..1023
    int h    = bid & 1;                 // j-half
    int b    = q >> 8;
    int i0   = (q & 255) * NW;
    int j0   = h * JH;

    // ---------------- Phase 0: stage inp rows + Wt, compute Eq tile ---------
    if (t < 64)
        ((float4*)sh.pre.in)[t] =
            ((const float4*)(inp + (size_t)(b * LL + i0) * DD))[t];
    ((float4*)sh.pre.wt)[t]       = ((const float4*)Wt)[t];
    ((float4*)sh.pre.wt)[t + 256] = ((const float4*)Wt)[t + 256];
    __syncthreads();                                             // B0
    if (t < NW * UU) {
        int r = t >> 5, u = t & 31;
        float qq = 0.f;
#pragma unroll
        for (int d = 0; d < DD; ++d)
            qq = fmaf(sh.pre.in[r][d], sh.pre.wt[d][u], qq);
        s_eq[r][u] = __expf(2.f * (qq + bh[u]));
    }
    __syncthreads();    // B1: eq ready; pre-union dead -> sh.at writable

    // eq for THIS wave's row -> 32 SGPRs via readlane (lane u holds eq[u])
    float eqv = s_eq[w][lane & 31];
    float sq[UU];
#pragma unroll
    for (int u = 0; u < UU; ++u)
        sq[u] = __uint_as_float(
            __builtin_amdgcn_readlane(__float_as_uint(eqv), u));

    // ---------------- Phase A: scores, all-register, zero LDS ---------------
    const float* ekb = Ek + ((size_t)(b * LL) + j0) * UU;
    float e[NTILE];
#pragma unroll 2
    for (int tile = 0; tile < NTILE; ++tile) {
        const float4* ekp =
            (const float4*)(ekb + (size_t)(tile * 64 + lane) * UU);
        float4 ek[8];
#pragma unroll
        for (int u4 = 0; u4 < 8; ++u4) ek[u4] = ekp[u4];   // 1 base, imm offs
        float acc = 0.f;
#pragma unroll
        for (int u4 = 0; u4 < 8; ++u4) {
            float4 wav = *(const float4*)(Wa + u4 * 4);    // hoisted s_load
            float p  = fmaf(sq[u4 * 4 + 0], ek[u4].x, 1.f);
            float qq = fmaf(sq[u4 * 4 + 1], ek[u4].y, 1.f);
            float r  = fmaf(sq[u4 * 4 + 2], ek[u4].z, 1.f);
            float s  = fmaf(sq[u4 * 4 + 3], ek[u4].w, 1.f);
            float n01 = fmaf(wav.x, qq, wav.y * p);
            float n23 = fmaf(wav.z, s, wav.w * r);
            float pq = p * qq, rs = r * s;
            float num = fmaf(n01, rs, n23 * pq);
            acc = fmaf(num, __builtin_amdgcn_rcpf(pq * rs), acc);
        }
        e[tile] = -2.f * acc;
    }

    // ---------------- In-wave, in-register partial softmax ------------------
    float rmax = e[0];
#pragma unroll
    for (int tile = 1; tile < NTILE; ++tile) rmax = fmaxf(rmax, e[tile]);
#pragma unroll
    for (int m2 = 32; m2 >= 1; m2 >>= 1)
        rmax = fmaxf(rmax, __shfl_xor(rmax, m2, 64));
    float sum = 0.f;
#pragma unroll
    for (int tile = 0; tile < NTILE; ++tile) {
        e[tile] = __expf(e[tile] - rmax);       // unnormalized ex, in regs
        sum += e[tile];
    }
#pragma unroll
    for (int m2 = 32; m2 >= 1; m2 >>= 1)
        sum += __shfl_xor(sum, m2, 64);
    if (lane == 0) {
        pm[bid * NW + w] = rmax;
        ps[bid * NW + w] = sum;
    }

    // single transposed write pass: at[j][w] (8-way bank conflict, 8 insts)
#pragma unroll
    for (int tile = 0; tile < NTILE; ++tile)
        sh.at[tile * 64 + lane][w] = e[tile];
    __syncthreads();                    // B2: full ex^T table visible

    // ---------------- Phase B: po = ex @ x, 1 ds_read_b128 per iter ---------
    int dq = t & 15;        // d-quad
    int g  = t >> 4;        // j-group 0..15
    const float4* inp4 = (const float4*)(inp + (size_t)b * LL * DD);
    float4 v[NW];
#pragma unroll
    for (int i = 0; i < NW; ++i) v[i] = (float4){0.f, 0.f, 0.f, 0.f};

#pragma unroll 4
    for (int jj = 0; jj < JH / 16; ++jj) {
        int jl = jj * 16 + g;
        float4 x = inp4[(size_t)(j0 + jl) * 16 + dq];
        float4 a = *(const float4*)(&sh.at[jl][0]);   // all 4 rows, one b128
        v[0].x = fmaf(a.x, x.x, v[0].x); v[0].y = fmaf(a.x, x.y, v[0].y);
        v[0].z = fmaf(a.x, x.z, v[0].z); v[0].w = fmaf(a.x, x.w, v[0].w);
        v[1].x = fmaf(a.y, x.x, v[1].x); v[1].y = fmaf(a.y, x.y, v[1].y);
        v[1].z = fmaf(a.y, x.z, v[1].z); v[1].w = fmaf(a.y, x.w, v[1].w);
        v[2].x = fmaf(a.z, x.x, v[2].x); v[2].y = fmaf(a.z, x.y, v[2].y);
        v[2].z = fmaf(a.z, x.z, v[2].z); v[2].w = fmaf(a.z, x.w, v[2].w);
        v[3].x = fmaf(a.w, x.x, v[3].x); v[3].y = fmaf(a.w, x.y, v[3].y);
        v[3].z = fmaf(a.w, x.z, v[3].z); v[3].w = fmaf(a.w, x.w, v[3].w);
    }

    // reduce the 4 j-groups within each wave (lane bits 4,5)
#pragma unroll
    for (int i = 0; i < NW; ++i) {
        v[i].x += __shfl_xor(v[i].x, 16, 64); v[i].y += __shfl_xor(v[i].y, 16, 64);
        v[i].z += __shfl_xor(v[i].z, 16, 64); v[i].w += __shfl_xor(v[i].w, 16, 64);
        v[i].x += __shfl_xor(v[i].x, 32, 64); v[i].y += __shfl_xor(v[i].y, 32, 64);
        v[i].z += __shfl_xor(v[i].z, 32, 64); v[i].w += __shfl_xor(v[i].w, 32, 64);
    }
    if (lane < 16) {
#pragma unroll
        for (int i = 0; i < NW; ++i) s_v[w][i][dq] = v[i];
    }
    __syncthreads();                                             // B3

    // final cross-wave reduce + coalesced store of partial o
    int i = t >> 6;       // 0..3
    int d = t & 63;       // 0..63
    const float* svf = (const float*)s_v;
    float r = 0.f;
#pragma unroll
    for (int w2 = 0; w2 < NW; ++w2) r += svf[w2 * (NW * 64) + i * 64 + d];
    po[(size_t)bid * (NW * DD) + i * DD + d] = r;
}

// ---------------------------------------------------------------------------
// K3: merge halves: out = (o0*w0 + o1*w1) / (s0*w0 + s1*w1 + 1e-8),
// w_h = exp(m_h - max(m0,m1)). Matches the reference's ex/(sum+1e-8).
// ---------------------------------------------------------------------------
__global__ __launch_bounds__(256) void combine_kernel(
    const float* __restrict__ po, const float* __restrict__ pm,
    const float* __restrict__ ps, float* __restrict__ out)
{
    int gid = blockIdx.x * 256 + threadIdx.x;   // 0 .. B*L*DD-1
    int d   = gid & 63;
    int row = gid >> 6;          // 0..4095
    int q   = row >> 2;          // row-quad
    int i   = row & 3;
    int b0  = q * 2, b1 = q * 2 + 1;
    float m0 = pm[b0 * NW + i], m1 = pm[b1 * NW + i];
    float s0 = ps[b0 * NW + i], s1 = ps[b1 * NW + i];
    float m  = fmaxf(m0, m1);
    float w0 = __expf(m0 - m), w1 = __expf(m1 - m);
    float s  = fmaf(s0, w0, s1 * w1) + 1e-8f;
    float o0 = po[(size_t)b0 * (NW * DD) + i * DD + d];
    float o1 = po[(size_t)b1 * (NW * DD) + i * DD + d];
    out[(size_t)row * DD + d] = fmaf(o0, w0, o1 * w1) * __builtin_amdgcn_rcpf(s);
}

// ---------------------------------------------------------------------------
extern "C" void kernel_launch(void* const* d_in, const int* in_sizes, int n_in,
                              void* d_out, int out_size, void* d_ws, size_t ws_size,
                              hipStream_t stream) {
    const float* inp = (const float*)d_in[0];
    const float* Wt  = (const float*)d_in[1];
    const float* Wx  = (const float*)d_in[2];
    const float* Wa  = (const float*)d_in[3];
    const float* bh  = (const float*)d_in[4];
    // d_in[5] = ba (cancels in softmax), d_in[6] = attention_width (dead code)
    float* out = (float*)d_out;

    float* Ek  = (float*)d_ws;                        // 512 KB
    float* po  = Ek + (size_t)BB * LL * UU;           // 2048*256 floats = 2 MB
    float* pm  = po + (size_t)2048 * NW * DD;         // 32 KB
    float* ps  = pm + (size_t)2048 * NW;              // 32 KB

    precompute_kernel<<<BB * LL / 8, 256, 0, stream>>>(inp, Wx, Ek);
    attn_partial_kernel<<<2 * BB * LL / NW, NT, 0, stream>>>(
        Ek, inp, Wt, Wa, bh, po, pm, ps);
    combine_kernel<<<BB * LL * DD / 256, 256, 0, stream>>>(po, pm, ps, out);
}